// Round 3
// baseline (440.908 us; speedup 1.0000x reference)
//
#include <hip/hip_runtime.h>
#include <hip/hip_bf16.h>

typedef _Float16 half8 __attribute__((ext_vector_type(8)));
typedef float floatx4 __attribute__((ext_vector_type(4)));

#define B_ 4
#define C_ 256
#define N_ 4096

// workspace layout (bytes); total ~75.5 MB
#define OFF_FN   ((size_t)0)                      // 4*4096*256 fp16 = 8 MB
#define OFF_PROB ((size_t)(8u << 20))             // 16384 fp32 = 64 KB
#define OFF_SIM  ((size_t)((8u << 20) + 65536))   // 4096*4096 fp32 = 64 MB (per-batch chunk, reused)
#define OFF_INV  OFF_SIM                          // inv[16384] overlays sim (consumed before gram runs)

__device__ __forceinline__ void gl_lds16(const void* g, void* l) {
    __builtin_amdgcn_global_load_lds(
        (const __attribute__((address_space(1))) void*)g,
        (__attribute__((address_space(3))) void*)l,
        16, 0, 0);
}

__device__ __forceinline__ void topk8_insert(float v, int j, float tv[8], int tj[8], float& tmin) {
    if (v > tmin) {
        bool done = false;
#pragma unroll
        for (int s = 0; s < 8; ++s) {
            bool take = (!done) && (tv[s] == tmin);
            if (take) { tv[s] = v; tj[s] = j; }
            done = done || take;
        }
        float nm = tv[0];
#pragma unroll
        for (int s = 1; s < 8; ++s) nm = fminf(nm, tv[s]);
        tmin = nm;
    }
}

// ---------------- Kernel 1a: row norms + sigmoid + out zero ----------------
__global__ __launch_bounds__(256) void norm_kernel(const float* __restrict__ feats,
                                                   const float* __restrict__ logits,
                                                   float* __restrict__ inv,
                                                   float* __restrict__ prob,
                                                   float* __restrict__ out) {
    int gid = blockIdx.x * 256 + threadIdx.x;       // 0..16383 = (b, i)
    if (gid == 0) out[0] = 0.f;                     // zero the loss accumulator (before any scan)
    int b = gid >> 12, i = gid & (N_ - 1);
    const float* fb = feats + (size_t)b * C_ * N_ + i;
    float ss = 0.f;
#pragma unroll 8
    for (int c = 0; c < C_; ++c) { float v = fb[(size_t)c * N_]; ss += v * v; }
    inv[gid] = 1.f / fmaxf(sqrtf(ss), 1e-12f);
    float lg = logits[gid];
    prob[gid] = 1.f / (1.f + expf(-lg));
}

// ---------------- Kernel 1b: transpose-convert to fp16 n x c rows ----------------
__global__ __launch_bounds__(256) void convert_kernel(const float* __restrict__ feats,
                                                      const float* __restrict__ inv,
                                                      _Float16* __restrict__ fn) {
    int g = blockIdx.x * 256 + threadIdx.x;        // 0..524287
    int row = g >> 5;                              // b*4096 + i
    int c0 = (g & 31) * 8;
    int b = row >> 12, i = row & (N_ - 1);
    const float* fb = feats + (size_t)b * C_ * N_ + (size_t)c0 * N_ + i;
    float s = inv[row];
    half8 h;
#pragma unroll
    for (int j = 0; j < 8; ++j) h[j] = (_Float16)(fb[(size_t)j * N_] * s);
    *(half8*)(fn + (size_t)row * C_ + c0) = h;
}

// ---------------- Kernel 2: pure MFMA gram for one batch -> sim (fp32 4096x4096) ----------------
// m97 recipe: 128x128 tile, BK=32, global_load_lds width=16, unpadded LDS (bank-balanced:
// 64B rows -> start banks 4*((2*m16+... )) spread evenly, ds_read_b128 conflict-free).
__global__ __launch_bounds__(256) void gram_kernel(const _Float16* __restrict__ fnb,
                                                   float* __restrict__ sim) {
    __shared__ __align__(16) _Float16 As[128 * 32];
    __shared__ __align__(16) _Float16 Bs[128 * 32];

    const int t    = threadIdx.x;
    const int lane = t & 63;
    const int w    = t >> 6;
    const int m16  = lane & 15;
    const int q    = lane >> 4;

    const int it = blockIdx.x & 31, jt = blockIdx.x >> 5;
    const int i0 = it * 128, j0 = jt * 128;

    // staging: wave w covers tile rows [w*16, w*16+16) and +64; lane -> (row, 16B col chunk)
    // LDS dst byte = w*1024 + lane*16 (contiguous in lane order -> valid for global_load_lds)
    const int srow = w * 16 + (lane >> 2);
    const int scol = (lane & 3) * 8;               // halfs

    floatx4 acc[2][8];
#pragma unroll
    for (int ri = 0; ri < 2; ++ri)
#pragma unroll
        for (int jj = 0; jj < 8; ++jj) acc[ri][jj] = floatx4{0.f, 0.f, 0.f, 0.f};

    for (int kc = 0; kc < 8; ++kc) {
        const _Float16* gA = fnb + (size_t)(i0 + srow) * C_ + kc * 32 + scol;
        const _Float16* gB = fnb + (size_t)(j0 + srow) * C_ + kc * 32 + scol;
        _Float16* lA = As + srow * 32 + scol;
        _Float16* lB = Bs + srow * 32 + scol;
        gl_lds16(gA,            lA);
        gl_lds16(gA + 64 * C_,  lA + 64 * 32);
        gl_lds16(gB,            lB);
        gl_lds16(gB + 64 * C_,  lB + 64 * 32);
        __syncthreads();                            // compiler drains vmcnt before barrier

        half8 a0 = *(const half8*)&As[(w * 32 + m16) * 32 + q * 8];
        half8 a1 = *(const half8*)&As[(w * 32 + 16 + m16) * 32 + q * 8];
#pragma unroll
        for (int jj = 0; jj < 8; ++jj) {
            half8 bf = *(const half8*)&Bs[(jj * 16 + m16) * 32 + q * 8];
            acc[0][jj] = __builtin_amdgcn_mfma_f32_16x16x32_f16(a0, bf, acc[0][jj], 0, 0, 0);
            acc[1][jj] = __builtin_amdgcn_mfma_f32_16x16x32_f16(a1, bf, acc[1][jj], 0, 0, 0);
        }
        __syncthreads();
    }

    // epilogue: C/D layout col=lane&15, row=q*4+reg (verified exact in rounds 1-2)
#pragma unroll
    for (int jj = 0; jj < 8; ++jj)
#pragma unroll
        for (int ri = 0; ri < 2; ++ri)
#pragma unroll
            for (int r = 0; r < 4; ++r) {
                int row = i0 + w * 32 + ri * 16 + q * 4 + r;
                int col = j0 + jj * 16 + m16;
                sim[(size_t)row * N_ + col] = acc[ri][jj][r];
            }
}

// ---------------- Kernel 3: wave-per-row top-8 + loss accumulate ----------------
// 64 lanes stream one sim row (coalesced float4), per-lane top-8, then 8 wave-argmax
// extractions gather prob and accumulate |p_i - p_j| directly. No barriers, no LDS.
__global__ __launch_bounds__(256) void scan_kernel(const float* __restrict__ sim,
                                                   const float* __restrict__ prob,
                                                   int b,
                                                   float* __restrict__ out) {
    const int t = threadIdx.x;
    const int lane = t & 63;
    const int w = t >> 6;
    const int r = blockIdx.x * 4 + w;              // row 0..4095

    float tv[8]; int tj[8]; float tmin = -__builtin_inff();
#pragma unroll
    for (int s = 0; s < 8; ++s) { tv[s] = -__builtin_inff(); tj[s] = 0; }

    const float4* sr = (const float4*)(sim + (size_t)r * N_);
    float4 v = sr[lane];
    for (int tt = 0; tt < 16; ++tt) {
        float4 nx;
        if (tt < 15) nx = sr[(tt + 1) * 64 + lane];
        int jb = ((tt * 64) + lane) * 4;
        topk8_insert(v.x, jb + 0, tv, tj, tmin);
        topk8_insert(v.y, jb + 1, tv, tj, tmin);
        topk8_insert(v.z, jb + 2, tv, tj, tmin);
        topk8_insert(v.w, jb + 3, tv, tj, tmin);
        v = nx;
    }

    const float* pb = prob + b * N_;
    float p_r = pb[r];
    float psum = 0.f;
#pragma unroll 1
    for (int k = 0; k < 8; ++k) {
        float m = tv[0];
#pragma unroll
        for (int s = 1; s < 8; ++s) m = fmaxf(m, tv[s]);
        float M = m;
#pragma unroll
        for (int off = 32; off; off >>= 1) M = fmaxf(M, __shfl_xor(M, off));
        unsigned long long mask = __ballot(m == M);
        int winner = __ffsll((unsigned long long)mask) - 1;
        if (lane == winner) {
            bool done = false;
#pragma unroll
            for (int s = 0; s < 8; ++s) {
                bool take = (!done) && (tv[s] == M);
                if (take) { psum += fabsf(p_r - pb[tj[s]]); tv[s] = -__builtin_inff(); }
                done = done || take;
            }
        }
    }
    // wave-reduce psum, one atomic per wave
#pragma unroll
    for (int off = 32; off; off >>= 1) psum += __shfl_xor(psum, off);
    if (lane == 0) atomicAdd(out, psum * (1.f / (B_ * N_ * 8.0f)));
}

extern "C" void kernel_launch(void* const* d_in, const int* in_sizes, int n_in,
                              void* d_out, int out_size, void* d_ws, size_t ws_size,
                              hipStream_t stream) {
    const float* feats  = (const float*)d_in[0];
    const float* logits = (const float*)d_in[1];
    float* out = (float*)d_out;
    char* ws = (char*)d_ws;
    _Float16* fn  = (_Float16*)(ws + OFF_FN);
    float* prob   = (float*)(ws + OFF_PROB);
    float* sim    = (float*)(ws + OFF_SIM);
    float* inv    = (float*)(ws + OFF_INV);   // overlays sim; consumed before gram writes

    norm_kernel<<<64, 256, 0, stream>>>(feats, logits, inv, prob, out);
    convert_kernel<<<2048, 256, 0, stream>>>(feats, inv, fn);
    for (int b = 0; b < B_; ++b) {
        gram_kernel<<<1024, 256, 0, stream>>>(fn + (size_t)b * N_ * C_, sim);
        scan_kernel<<<1024, 256, 0, stream>>>(sim, prob, b, out);
    }
}

// Round 4
// 267.825 us; speedup vs baseline: 1.6463x; 1.6463x over previous
//
#include <hip/hip_runtime.h>
#include <hip/hip_bf16.h>

typedef _Float16 half8 __attribute__((ext_vector_type(8)));
typedef float floatx4 __attribute__((ext_vector_type(4)));

#define B_ 4
#define C_ 256
#define N_ 4096

// workspace layout (bytes); total ~40.3 MB
#define OFF_FN    ((size_t)0)                     // 4*4096*256 fp16 = 8 MB
#define OFF_PROB  ((size_t)(8u << 20))            // 16384 fp32 = 64 KB
#define OFF_PART  (OFF_PROB + 65536)              // 4096 fp32 block partials = 16 KB
#define OFF_SIMH  (OFF_PART + 16384)              // 4096*4096 fp16 = 32 MB (per-batch, reused)
#define OFF_INV   OFF_SIMH                        // inv[16384] overlays simh (consumed before gram)

__device__ __forceinline__ void gl_lds16(const void* g, void* l) {
    __builtin_amdgcn_global_load_lds(
        (const __attribute__((address_space(1))) void*)g,
        (__attribute__((address_space(3))) void*)l,
        16, 0, 0);
}

__device__ __forceinline__ void topk8_insert(float v, int j, float tv[8], int tj[8], float& tmin) {
    if (v > tmin) {
        bool done = false;
#pragma unroll
        for (int s = 0; s < 8; ++s) {
            bool take = (!done) && (tv[s] == tmin);
            if (take) { tv[s] = v; tj[s] = j; }
            done = done || take;
        }
        float nm = tv[0];
#pragma unroll
        for (int s = 1; s < 8; ++s) nm = fminf(nm, tv[s]);
        tmin = nm;
    }
}

// ---------------- Kernel 1a: row norms + sigmoid ----------------
__global__ __launch_bounds__(256) void norm_kernel(const float* __restrict__ feats,
                                                   const float* __restrict__ logits,
                                                   float* __restrict__ inv,
                                                   float* __restrict__ prob) {
    int gid = blockIdx.x * 256 + threadIdx.x;       // 0..16383 = (b, i)
    int b = gid >> 12, i = gid & (N_ - 1);
    const float* fb = feats + (size_t)b * C_ * N_ + i;
    float ss = 0.f;
#pragma unroll 8
    for (int c = 0; c < C_; ++c) { float v = fb[(size_t)c * N_]; ss += v * v; }
    inv[gid] = 1.f / fmaxf(sqrtf(ss), 1e-12f);
    float lg = logits[gid];
    prob[gid] = 1.f / (1.f + expf(-lg));
}

// ---------------- Kernel 1b: transpose-convert to fp16 n x c rows ----------------
__global__ __launch_bounds__(256) void convert_kernel(const float* __restrict__ feats,
                                                      const float* __restrict__ inv,
                                                      _Float16* __restrict__ fn) {
    int g = blockIdx.x * 256 + threadIdx.x;        // 0..524287
    int row = g >> 5;                              // b*4096 + i
    int c0 = (g & 31) * 8;
    int b = row >> 12, i = row & (N_ - 1);
    const float* fb = feats + (size_t)b * C_ * N_ + (size_t)c0 * N_ + i;
    float s = inv[row];
    half8 h;
#pragma unroll
    for (int j = 0; j < 8; ++j) h[j] = (_Float16)(fb[(size_t)j * N_] * s);
    *(half8*)(fn + (size_t)row * C_ + c0) = h;
}

// ---------------- Kernel 2: MFMA gram for one batch -> simh (fp16 4096x4096) ----------------
__global__ __launch_bounds__(256) void gram_kernel(const _Float16* __restrict__ fnb,
                                                   _Float16* __restrict__ simh) {
    __shared__ __align__(16) _Float16 As[128 * 32];
    __shared__ __align__(16) _Float16 Bs[128 * 32];

    const int t    = threadIdx.x;
    const int lane = t & 63;
    const int w    = t >> 6;
    const int m16  = lane & 15;
    const int q    = lane >> 4;

    const int it = blockIdx.x & 31, jt = blockIdx.x >> 5;
    const int i0 = it * 128, j0 = jt * 128;

    // staging: LDS dst byte = w*1024 + lane*16 (contiguous in lane order -> valid for global_load_lds)
    const int srow = w * 16 + (lane >> 2);
    const int scol = (lane & 3) * 8;               // halfs

    floatx4 acc[2][8];
#pragma unroll
    for (int ri = 0; ri < 2; ++ri)
#pragma unroll
        for (int jj = 0; jj < 8; ++jj) acc[ri][jj] = floatx4{0.f, 0.f, 0.f, 0.f};

    for (int kc = 0; kc < 8; ++kc) {
        const _Float16* gA = fnb + (size_t)(i0 + srow) * C_ + kc * 32 + scol;
        const _Float16* gB = fnb + (size_t)(j0 + srow) * C_ + kc * 32 + scol;
        _Float16* lA = As + srow * 32 + scol;
        _Float16* lB = Bs + srow * 32 + scol;
        gl_lds16(gA,            lA);
        gl_lds16(gA + 64 * C_,  lA + 64 * 32);
        gl_lds16(gB,            lB);
        gl_lds16(gB + 64 * C_,  lB + 64 * 32);
        __syncthreads();

        half8 a0 = *(const half8*)&As[(w * 32 + m16) * 32 + q * 8];
        half8 a1 = *(const half8*)&As[(w * 32 + 16 + m16) * 32 + q * 8];
#pragma unroll
        for (int jj = 0; jj < 8; ++jj) {
            half8 bf = *(const half8*)&Bs[(jj * 16 + m16) * 32 + q * 8];
            acc[0][jj] = __builtin_amdgcn_mfma_f32_16x16x32_f16(a0, bf, acc[0][jj], 0, 0, 0);
            acc[1][jj] = __builtin_amdgcn_mfma_f32_16x16x32_f16(a1, bf, acc[1][jj], 0, 0, 0);
        }
        __syncthreads();
    }

    // epilogue: C/D layout col=lane&15, row=q*4+reg; store fp16 (halves write traffic)
#pragma unroll
    for (int jj = 0; jj < 8; ++jj)
#pragma unroll
        for (int ri = 0; ri < 2; ++ri)
#pragma unroll
            for (int r = 0; r < 4; ++r) {
                int row = i0 + w * 32 + ri * 16 + q * 4 + r;
                int col = j0 + jj * 16 + m16;
                simh[(size_t)row * N_ + col] = (_Float16)acc[ri][jj][r];
            }
}

// ---------------- Kernel 3: wave-per-row top-8 + per-block partial loss ----------------
// 8 independent preloaded 16B loads per lane (latency hidden), no atomics.
__global__ __launch_bounds__(256) void scan_kernel(const _Float16* __restrict__ simh,
                                                   const float* __restrict__ prob,
                                                   int b,
                                                   float* __restrict__ partials) {
    __shared__ float red[4];
    const int t = threadIdx.x;
    const int lane = t & 63;
    const int w = t >> 6;
    const int r = blockIdx.x * 4 + w;              // row 0..4095

    const half8* sr = (const half8*)(simh + (size_t)r * N_);
    half8 h[8];
#pragma unroll
    for (int c = 0; c < 8; ++c) h[c] = sr[c * 64 + lane];   // 8 outstanding 16B loads

    float tv[8]; int tj[8]; float tmin = -__builtin_inff();
#pragma unroll
    for (int s = 0; s < 8; ++s) { tv[s] = -__builtin_inff(); tj[s] = 0; }

#pragma unroll
    for (int c = 0; c < 8; ++c) {
        int jb = (c * 64 + lane) * 8;
#pragma unroll
        for (int e = 0; e < 8; ++e)
            topk8_insert((float)h[c][e], jb + e, tv, tj, tmin);
    }

    const float* pb = prob + b * N_;
    float p_r = pb[r];
    float psum = 0.f;
#pragma unroll 1
    for (int k = 0; k < 8; ++k) {
        float m = tv[0];
#pragma unroll
        for (int s = 1; s < 8; ++s) m = fmaxf(m, tv[s]);
        float M = m;
#pragma unroll
        for (int off = 32; off; off >>= 1) M = fmaxf(M, __shfl_xor(M, off));
        unsigned long long mask = __ballot(m == M);
        int winner = __ffsll((unsigned long long)mask) - 1;
        if (lane == winner) {
            bool done = false;
#pragma unroll
            for (int s = 0; s < 8; ++s) {
                bool take = (!done) && (tv[s] == M);
                if (take) { psum += fabsf(p_r - pb[tj[s]]); tv[s] = -__builtin_inff(); }
                done = done || take;
            }
        }
    }
    // wave-reduce psum -> LDS -> one block partial (no atomics)
#pragma unroll
    for (int off = 32; off; off >>= 1) psum += __shfl_xor(psum, off);
    if (lane == 0) red[w] = psum;
    __syncthreads();
    if (t == 0) partials[b * 1024 + blockIdx.x] = red[0] + red[1] + red[2] + red[3];
}

// ---------------- Kernel 4: final reduce ----------------
__global__ __launch_bounds__(256) void final_kernel(const float* __restrict__ partials,
                                                    float* __restrict__ out) {
    __shared__ float red[256];
    int t = threadIdx.x;
    float s = 0.f;
#pragma unroll
    for (int k = 0; k < 16; ++k) s += partials[k * 256 + t];
    red[t] = s;
    __syncthreads();
    for (int off = 128; off > 0; off >>= 1) {
        if (t < off) red[t] += red[t + off];
        __syncthreads();
    }
    if (t == 0) out[0] = red[0] * (1.f / (B_ * N_ * 8.0f));
}

extern "C" void kernel_launch(void* const* d_in, const int* in_sizes, int n_in,
                              void* d_out, int out_size, void* d_ws, size_t ws_size,
                              hipStream_t stream) {
    const float* feats  = (const float*)d_in[0];
    const float* logits = (const float*)d_in[1];
    float* out = (float*)d_out;
    char* ws = (char*)d_ws;
    _Float16* fn   = (_Float16*)(ws + OFF_FN);
    float* prob    = (float*)(ws + OFF_PROB);
    float* parts   = (float*)(ws + OFF_PART);
    _Float16* simh = (_Float16*)(ws + OFF_SIMH);
    float* inv     = (float*)(ws + OFF_INV);   // overlays simh; consumed before gram writes

    norm_kernel<<<64, 256, 0, stream>>>(feats, logits, inv, prob);
    convert_kernel<<<2048, 256, 0, stream>>>(feats, inv, fn);
    for (int b = 0; b < B_; ++b) {
        gram_kernel<<<1024, 256, 0, stream>>>(fn + (size_t)b * N_ * C_, simh);
        scan_kernel<<<1024, 256, 0, stream>>>(simh, prob, b, parts);
    }
    final_kernel<<<1, 256, 0, stream>>>(parts, out);
}

// Round 5
// 256.386 us; speedup vs baseline: 1.7197x; 1.0446x over previous
//
#include <hip/hip_runtime.h>
#include <hip/hip_bf16.h>

typedef _Float16 half8 __attribute__((ext_vector_type(8)));
typedef _Float16 half4 __attribute__((ext_vector_type(4)));
typedef float floatx4 __attribute__((ext_vector_type(4)));

#define B_ 4
#define C_ 256
#define N_ 4096

// workspace layout (bytes); total ~40.3 MB
#define OFF_FN    ((size_t)0)                     // 4*4096*256 fp16 = 8 MB
#define OFF_PROB  ((size_t)(8u << 20))            // 16384 fp32 = 64 KB
#define OFF_PART  (OFF_PROB + 65536)              // 4096 fp32 block partials = 16 KB
#define OFF_SIMH  (OFF_PART + 16384)              // 4096*4096 fp16 = 32 MB (per-batch, reused)

__device__ __forceinline__ void gl_lds16(const void* g, void* l) {
    __builtin_amdgcn_global_load_lds(
        (const __attribute__((address_space(1))) void*)g,
        (__attribute__((address_space(3))) void*)l,
        16, 0, 0);
}

__device__ __forceinline__ void topk8_insert(float v, int j, float tv[8], int tj[8], float& tmin) {
    if (v > tmin) {
        bool done = false;
#pragma unroll
        for (int s = 0; s < 8; ++s) {
            bool take = (!done) && (tv[s] == tmin);
            if (take) { tv[s] = v; tj[s] = j; }
            done = done || take;
        }
        float nm = tv[0];
#pragma unroll
        for (int s = 1; s < 8; ++s) nm = fminf(nm, tv[s]);
        tmin = nm;
    }
}

// ---------------- Kernel 1: fused prep — reads feats ONCE ----------------
// block = 64 i-values x all 256 channels. LDS transpose tile (fp32, stride 68
// for alignment + near-conflict-free access), column reduce -> inv norm,
// fp16 convert, contiguous row writes. Also sigmoid(logits) -> prob.
#define TS 68   // tile stride (floats): 16B-aligned float4 rows, banks spread
__global__ __launch_bounds__(256) void prep_kernel(const float* __restrict__ feats,
                                                   const float* __restrict__ logits,
                                                   _Float16* __restrict__ fn,
                                                   float* __restrict__ prob) {
    __shared__ __align__(16) float T[C_ * TS];    // 69.6 KB
    __shared__ float S[256];
    __shared__ float I[64];

    const int t  = threadIdx.x;
    const int b  = blockIdx.x >> 6;
    const int i0 = (blockIdx.x & 63) * 64;
    const float* fb = feats + (size_t)b * C_ * N_;

    // stage 256x64 fp32 tile: 16 independent float4 loads/thread, coalesced 256B/row
#pragma unroll
    for (int k = 0; k < 16; ++k) {
        int ch = t + k * 256;
        int row = ch >> 4, col4 = ch & 15;
        float4 v = *(const float4*)(fb + (size_t)row * N_ + i0 + col4 * 4);
        *(float4*)&T[row * TS + col4 * 4] = v;
    }
    __syncthreads();

    // per-i sum of squares: wave w covers c-range [w*64, w*64+64), lane = i
    {
        int i = t & 63, cq = t >> 6;
        float ss = 0.f;
#pragma unroll 8
        for (int j = 0; j < 64; ++j) { float v = T[(cq * 64 + j) * TS + i]; ss += v * v; }
        S[cq * 64 + i] = ss;
    }
    __syncthreads();
    if (t < 64) {
        float ss = S[t] + S[64 + t] + S[128 + t] + S[192 + t];
        I[t] = 1.f / fmaxf(sqrtf(ss), 1e-12f);
        float lg = logits[b * N_ + i0 + t];
        prob[b * N_ + i0 + t] = 1.f / (1.f + expf(-lg));
    }
    __syncthreads();

    // write fn rows: 4 threads/row, 64 ch each -> 8 half8 stores, rows contiguous
    {
        int i = t >> 2, chunk = t & 3;
        float s = I[i];
        _Float16* fr = fn + ((size_t)(b * N_ + i0 + i)) * C_ + chunk * 64;
#pragma unroll
        for (int v8 = 0; v8 < 8; ++v8) {
            half8 h;
#pragma unroll
            for (int e = 0; e < 8; ++e)
                h[e] = (_Float16)(T[(chunk * 64 + v8 * 8 + e) * TS + i] * s);
            *(half8*)(fr + v8 * 8) = h;
        }
    }
}

// ---------------- Kernel 2: MFMA gram, BK=64, XOR-swizzled LDS, symmetric-T store ----------------
__global__ __launch_bounds__(256) void gram_kernel(const _Float16* __restrict__ fnb,
                                                   _Float16* __restrict__ simh) {
    __shared__ __align__(16) _Float16 As[128 * 64];   // 16 KB
    __shared__ __align__(16) _Float16 Bs[128 * 64];   // 16 KB

    const int t    = threadIdx.x;
    const int lane = t & 63;
    const int w    = t >> 6;
    const int m16  = lane & 15;
    const int q    = lane >> 4;

    const int it = blockIdx.x & 31, jt = blockIdx.x >> 5;
    const int i0 = it * 128, j0 = jt * 128;

    // staging map: per issue r (32 rows), thread t -> row r*32+(t>>3), LDS slot chunk t&7.
    // source chunk is XOR-swizzled so frag reads hit all 32 banks (2-way only).
    const int srowb = t >> 3;                 // 0..31 within issue
    const int schunk = (t & 7) ^ (srowb & 7); // swizzled source 16B-chunk

    floatx4 acc[2][8];
#pragma unroll
    for (int ri = 0; ri < 2; ++ri)
#pragma unroll
        for (int jj = 0; jj < 8; ++jj) acc[ri][jj] = floatx4{0.f, 0.f, 0.f, 0.f};

    const int sw = m16 & 7;                   // reader swizzle key (row & 7 == m16 & 7)

    for (int kc = 0; kc < 4; ++kc) {
#pragma unroll
        for (int r = 0; r < 4; ++r) {
            int row = r * 32 + srowb;
            const _Float16* gA = fnb + (size_t)(i0 + row) * C_ + kc * 64 + schunk * 8;
            const _Float16* gB = fnb + (size_t)(j0 + row) * C_ + kc * 64 + schunk * 8;
            gl_lds16(gA, (char*)As + r * 4096 + t * 16);
            gl_lds16(gB, (char*)Bs + r * 4096 + t * 16);
        }
        __syncthreads();

#pragma unroll
        for (int kk = 0; kk < 2; ++kk) {
            half8 a0 = *(const half8*)&As[(w * 32 + m16) * 64 + ((kk * 4 + q) ^ sw) * 8];
            half8 a1 = *(const half8*)&As[(w * 32 + 16 + m16) * 64 + ((kk * 4 + q) ^ sw) * 8];
#pragma unroll
            for (int jj = 0; jj < 8; ++jj) {
                half8 bf = *(const half8*)&Bs[(jj * 16 + m16) * 64 + ((kk * 4 + q) ^ sw) * 8];
                acc[0][jj] = __builtin_amdgcn_mfma_f32_16x16x32_f16(a0, bf, acc[0][jj], 0, 0, 0);
                acc[1][jj] = __builtin_amdgcn_mfma_f32_16x16x32_f16(a1, bf, acc[1][jj], 0, 0, 0);
            }
        }
        __syncthreads();
    }

    // epilogue: sim is symmetric, so store C^T (= C). acc[ri][jj][0..3] are 4
    // consecutive ROWS at col jj*16+m16 -> one 8B half4 store each.
#pragma unroll
    for (int jj = 0; jj < 8; ++jj)
#pragma unroll
        for (int ri = 0; ri < 2; ++ri) {
            int col = j0 + jj * 16 + m16;
            int row = i0 + w * 32 + ri * 16 + q * 4;
            half4 h;
#pragma unroll
            for (int r = 0; r < 4; ++r) h[r] = (_Float16)acc[ri][jj][r];
            *(half4*)(simh + (size_t)col * N_ + row) = h;
        }
}

// ---------------- Kernel 3: wave-per-row top-8 + per-block partial loss ----------------
__global__ __launch_bounds__(256) void scan_kernel(const _Float16* __restrict__ simh,
                                                   const float* __restrict__ prob,
                                                   int b,
                                                   float* __restrict__ partials) {
    __shared__ float red[4];
    const int t = threadIdx.x;
    const int lane = t & 63;
    const int w = t >> 6;
    const int r = blockIdx.x * 4 + w;              // row 0..4095

    const half8* sr = (const half8*)(simh + (size_t)r * N_);
    half8 h[8];
#pragma unroll
    for (int c = 0; c < 8; ++c) h[c] = sr[c * 64 + lane];   // 8 outstanding 16B loads

    float tv[8]; int tj[8]; float tmin = -__builtin_inff();
#pragma unroll
    for (int s = 0; s < 8; ++s) { tv[s] = -__builtin_inff(); tj[s] = 0; }

#pragma unroll
    for (int c = 0; c < 8; ++c) {
        int jb = (c * 64 + lane) * 8;
#pragma unroll
        for (int e = 0; e < 8; ++e)
            topk8_insert((float)h[c][e], jb + e, tv, tj, tmin);
    }

    const float* pb = prob + b * N_;
    float p_r = pb[r];
    float psum = 0.f;
#pragma unroll 1
    for (int k = 0; k < 8; ++k) {
        float m = tv[0];
#pragma unroll
        for (int s = 1; s < 8; ++s) m = fmaxf(m, tv[s]);
        float M = m;
#pragma unroll
        for (int off = 32; off; off >>= 1) M = fmaxf(M, __shfl_xor(M, off));
        unsigned long long mask = __ballot(m == M);
        int winner = __ffsll((unsigned long long)mask) - 1;
        if (lane == winner) {
            bool done = false;
#pragma unroll
            for (int s = 0; s < 8; ++s) {
                bool take = (!done) && (tv[s] == M);
                if (take) { psum += fabsf(p_r - pb[tj[s]]); tv[s] = -__builtin_inff(); }
                done = done || take;
            }
        }
    }
#pragma unroll
    for (int off = 32; off; off >>= 1) psum += __shfl_xor(psum, off);
    if (lane == 0) red[w] = psum;
    __syncthreads();
    if (t == 0) partials[b * 1024 + blockIdx.x] = red[0] + red[1] + red[2] + red[3];
}

// ---------------- Kernel 4: final reduce ----------------
__global__ __launch_bounds__(256) void final_kernel(const float* __restrict__ partials,
                                                    float* __restrict__ out) {
    __shared__ float red[256];
    int t = threadIdx.x;
    float s = 0.f;
#pragma unroll
    for (int k = 0; k < 16; ++k) s += partials[k * 256 + t];
    red[t] = s;
    __syncthreads();
    for (int off = 128; off > 0; off >>= 1) {
        if (t < off) red[t] += red[t + off];
        __syncthreads();
    }
    if (t == 0) out[0] = red[0] * (1.f / (B_ * N_ * 8.0f));
}

extern "C" void kernel_launch(void* const* d_in, const int* in_sizes, int n_in,
                              void* d_out, int out_size, void* d_ws, size_t ws_size,
                              hipStream_t stream) {
    const float* feats  = (const float*)d_in[0];
    const float* logits = (const float*)d_in[1];
    float* out = (float*)d_out;
    char* ws = (char*)d_ws;
    _Float16* fn   = (_Float16*)(ws + OFF_FN);
    float* prob    = (float*)(ws + OFF_PROB);
    float* parts   = (float*)(ws + OFF_PART);
    _Float16* simh = (_Float16*)(ws + OFF_SIMH);

    prep_kernel<<<256, 256, 0, stream>>>(feats, logits, fn, prob);
    for (int b = 0; b < B_; ++b) {
        gram_kernel<<<1024, 256, 0, stream>>>(fn + (size_t)b * N_ * C_, simh);
        scan_kernel<<<1024, 256, 0, stream>>>(simh, prob, b, parts);
    }
    final_kernel<<<1, 256, 0, stream>>>(parts, out);
}

// Round 6
// 187.898 us; speedup vs baseline: 2.3465x; 1.3645x over previous
//
#include <hip/hip_runtime.h>
#include <hip/hip_bf16.h>

typedef _Float16 half8 __attribute__((ext_vector_type(8)));
typedef _Float16 half4 __attribute__((ext_vector_type(4)));
typedef unsigned short ushort8 __attribute__((ext_vector_type(8)));
typedef float floatx4 __attribute__((ext_vector_type(4)));

#define B_ 4
#define C_ 256
#define N_ 4096

// workspace layout (bytes); ws is 256 MiB (fill counter). total used ~144.1 MB
#define OFF_FN    ((size_t)0)                     // 4*4096*256 fp16 = 8 MB
#define OFF_PROB  ((size_t)(8u << 20))            // 16384 fp32 = 64 KB
#define OFF_PART  (OFF_PROB + 65536)              // 4096 fp32 block partials = 16 KB
#define OFF_SIMH  ((size_t)(16u << 20))           // 4 x 4096 x 4096 fp16 = 128 MB

__device__ __forceinline__ void gl_lds16(const void* g, void* l) {
    __builtin_amdgcn_global_load_lds(
        (const __attribute__((address_space(1))) void*)g,
        (__attribute__((address_space(3))) void*)l,
        16, 0, 0);
}

// order-preserving fp16->u16 flip, packed with 12-bit index (value-exact selection)
__device__ __forceinline__ uint32_t pack16(uint32_t bits, int idx) {
    uint32_t m = ((bits >> 15) * 0x7FFFu) + 0x8000u;   // neg->0xFFFF, pos->0x8000
    return ((bits ^ m) << 16) | (uint32_t)idx;
}

__device__ __forceinline__ void pk_insert(uint32_t u, uint32_t pk[8], uint32_t& pmin) {
    if (u > pmin) {
        bool done = false;
#pragma unroll
        for (int s = 0; s < 8; ++s) {
            bool take = (!done) && (pk[s] == pmin);
            if (take) pk[s] = u;
            done = done || take;
        }
        uint32_t nm = pk[0];
#pragma unroll
        for (int s = 1; s < 8; ++s) nm = min(nm, pk[s]);
        pmin = nm;
    }
}

// ---------------- Kernel 1: fused prep — reads feats once ----------------
#define TS 68
__global__ __launch_bounds__(256) void prep_kernel(const float* __restrict__ feats,
                                                   const float* __restrict__ logits,
                                                   _Float16* __restrict__ fn,
                                                   float* __restrict__ prob) {
    __shared__ __align__(16) float T[C_ * TS];
    __shared__ float S[256];
    __shared__ float I[64];

    const int t  = threadIdx.x;
    const int b  = blockIdx.x >> 6;
    const int i0 = (blockIdx.x & 63) * 64;
    const float* fb = feats + (size_t)b * C_ * N_;

#pragma unroll
    for (int k = 0; k < 16; ++k) {
        int ch = t + k * 256;
        int row = ch >> 4, col4 = ch & 15;
        float4 v = *(const float4*)(fb + (size_t)row * N_ + i0 + col4 * 4);
        *(float4*)&T[row * TS + col4 * 4] = v;
    }
    __syncthreads();
    {
        int i = t & 63, cq = t >> 6;
        float ss = 0.f;
#pragma unroll 8
        for (int j = 0; j < 64; ++j) { float v = T[(cq * 64 + j) * TS + i]; ss += v * v; }
        S[cq * 64 + i] = ss;
    }
    __syncthreads();
    if (t < 64) {
        float ss = S[t] + S[64 + t] + S[128 + t] + S[192 + t];
        I[t] = 1.f / fmaxf(sqrtf(ss), 1e-12f);
        float lg = logits[b * N_ + i0 + t];
        prob[b * N_ + i0 + t] = 1.f / (1.f + expf(-lg));
    }
    __syncthreads();
    {
        int i = t >> 2, chunk = t & 3;
        float s = I[i];
        _Float16* fr = fn + ((size_t)(b * N_ + i0 + i)) * C_ + chunk * 64;
#pragma unroll
        for (int v8 = 0; v8 < 8; ++v8) {
            half8 h;
#pragma unroll
            for (int e = 0; e < 8; ++e)
                h[e] = (_Float16)(T[(chunk * 64 + v8 * 8 + e) * TS + i] * s);
            *(half8*)(fr + v8 * 8) = h;
        }
    }
}

// ---------------- Kernel 2: MFMA gram, ALL batches in one dispatch ----------------
__global__ __launch_bounds__(256) void gram_kernel(const _Float16* __restrict__ fn,
                                                   _Float16* __restrict__ simh) {
    __shared__ __align__(16) _Float16 As[128 * 64];
    __shared__ __align__(16) _Float16 Bs[128 * 64];

    const int t    = threadIdx.x;
    const int lane = t & 63;
    const int w    = t >> 6;
    const int m16  = lane & 15;
    const int q    = lane >> 4;

    const int it = blockIdx.x & 31, jt = (blockIdx.x >> 5) & 31;
    const int b  = blockIdx.x >> 10;
    const int i0 = it * 128, j0 = jt * 128;
    const _Float16* fnb = fn + (size_t)b * N_ * C_;
    _Float16* simb = simh + (size_t)b * N_ * N_;

    const int srowb = t >> 3;
    const int schunk = (t & 7) ^ (srowb & 7);

    floatx4 acc[2][8];
#pragma unroll
    for (int ri = 0; ri < 2; ++ri)
#pragma unroll
        for (int jj = 0; jj < 8; ++jj) acc[ri][jj] = floatx4{0.f, 0.f, 0.f, 0.f};

    const int sw = m16 & 7;

    for (int kc = 0; kc < 4; ++kc) {
#pragma unroll
        for (int r = 0; r < 4; ++r) {
            int row = r * 32 + srowb;
            const _Float16* gA = fnb + (size_t)(i0 + row) * C_ + kc * 64 + schunk * 8;
            const _Float16* gB = fnb + (size_t)(j0 + row) * C_ + kc * 64 + schunk * 8;
            gl_lds16(gA, (char*)As + r * 4096 + t * 16);
            gl_lds16(gB, (char*)Bs + r * 4096 + t * 16);
        }
        __syncthreads();

#pragma unroll
        for (int kk = 0; kk < 2; ++kk) {
            half8 a0 = *(const half8*)&As[(w * 32 + m16) * 64 + ((kk * 4 + q) ^ sw) * 8];
            half8 a1 = *(const half8*)&As[(w * 32 + 16 + m16) * 64 + ((kk * 4 + q) ^ sw) * 8];
#pragma unroll
            for (int jj = 0; jj < 8; ++jj) {
                half8 bf = *(const half8*)&Bs[(jj * 16 + m16) * 64 + ((kk * 4 + q) ^ sw) * 8];
                acc[0][jj] = __builtin_amdgcn_mfma_f32_16x16x32_f16(a0, bf, acc[0][jj], 0, 0, 0);
                acc[1][jj] = __builtin_amdgcn_mfma_f32_16x16x32_f16(a1, bf, acc[1][jj], 0, 0, 0);
            }
        }
        __syncthreads();
    }

    // symmetric-transpose store: acc[ri][jj][0..3] = 4 consecutive rows at one col -> half4
#pragma unroll
    for (int jj = 0; jj < 8; ++jj)
#pragma unroll
        for (int ri = 0; ri < 2; ++ri) {
            int col = j0 + jj * 16 + m16;
            int row = i0 + w * 32 + ri * 16 + q * 4;
            half4 h;
#pragma unroll
            for (int r = 0; r < 4; ++r) h[r] = (_Float16)acc[ri][jj][r];
            *(half4*)(simb + (size_t)col * N_ + row) = h;
        }
}

// ---------------- Kernel 3: wave-per-row packed top-8 + loss, ALL batches ----------------
__global__ __launch_bounds__(256) void scan_kernel(const _Float16* __restrict__ simh,
                                                   const float* __restrict__ prob,
                                                   float* __restrict__ partials) {
    __shared__ float red[4];
    const int t = threadIdx.x;
    const int lane = t & 63;
    const int w = t >> 6;
    const int rg = blockIdx.x * 4 + w;             // 0..16383
    const int b = rg >> 12, r = rg & (N_ - 1);

    const half8* sr = (const half8*)(simh + ((size_t)b * N_ + r) * N_);
    half8 h[8];
#pragma unroll
    for (int c = 0; c < 8; ++c) h[c] = sr[c * 64 + lane];   // 8 outstanding 16B loads

    // seed top-8 from chunk 0 (value-exact packed u32: flipped fp16 bits | index)
    uint32_t pk[8];
    {
        ushort8 hb = __builtin_bit_cast(ushort8, h[0]);
#pragma unroll
        for (int s = 0; s < 8; ++s) pk[s] = pack16((uint32_t)hb[s], lane * 8 + s);
    }
    uint32_t pmin = pk[0];
#pragma unroll
    for (int s = 1; s < 8; ++s) pmin = min(pmin, pk[s]);

#pragma unroll
    for (int c = 1; c < 8; ++c) {
        ushort8 hb = __builtin_bit_cast(ushort8, h[c]);
        int jb = (c * 64 + lane) * 8;
#pragma unroll
        for (int e = 0; e < 8; ++e)
            pk_insert(pack16((uint32_t)hb[e], jb + e), pk, pmin);
    }

    // extraction: 8 wave-max rounds; winner self-identifies (packed values unique);
    // lane k gathers prob for the k-th pick (loads overlap across iterations)
    const float* pb = prob + b * N_;
    float p_r = pb[r];
    uint32_t m = pk[0];
#pragma unroll
    for (int s = 1; s < 8; ++s) m = max(m, pk[s]);

    float contrib = 0.f;
#pragma unroll
    for (int k = 0; k < 8; ++k) {
        uint32_t M = m;
#pragma unroll
        for (int off = 32; off; off >>= 1) M = max(M, (uint32_t)__shfl_xor((int)M, off));
        if (lane == k) contrib = fabsf(p_r - pb[M & 0xFFFu]);
        if (m == M) {
            bool done = false;
#pragma unroll
            for (int s = 0; s < 8; ++s) {
                bool take = (!done) && (pk[s] == M);
                if (take) pk[s] = 0u;
                done = done || take;
            }
            uint32_t nm = pk[0];
#pragma unroll
            for (int s = 1; s < 8; ++s) nm = max(nm, pk[s]);
            m = nm;
        }
    }
#pragma unroll
    for (int off = 32; off; off >>= 1) contrib += __shfl_xor(contrib, off);
    if (lane == 0) red[w] = contrib;
    __syncthreads();
    if (t == 0) partials[blockIdx.x] = red[0] + red[1] + red[2] + red[3];
}

// ---------------- Kernel 4: final reduce ----------------
__global__ __launch_bounds__(256) void final_kernel(const float* __restrict__ partials,
                                                    float* __restrict__ out) {
    __shared__ float red[256];
    int t = threadIdx.x;
    float s = 0.f;
#pragma unroll
    for (int k = 0; k < 16; ++k) s += partials[k * 256 + t];
    red[t] = s;
    __syncthreads();
    for (int off = 128; off > 0; off >>= 1) {
        if (t < off) red[t] += red[t + off];
        __syncthreads();
    }
    if (t == 0) out[0] = red[0] * (1.f / (B_ * N_ * 8.0f));
}

extern "C" void kernel_launch(void* const* d_in, const int* in_sizes, int n_in,
                              void* d_out, int out_size, void* d_ws, size_t ws_size,
                              hipStream_t stream) {
    const float* feats  = (const float*)d_in[0];
    const float* logits = (const float*)d_in[1];
    float* out = (float*)d_out;
    char* ws = (char*)d_ws;
    _Float16* fn   = (_Float16*)(ws + OFF_FN);
    float* prob    = (float*)(ws + OFF_PROB);
    float* parts   = (float*)(ws + OFF_PART);
    _Float16* simh = (_Float16*)(ws + OFF_SIMH);

    prep_kernel<<<256, 256, 0, stream>>>(feats, logits, fn, prob);
    gram_kernel<<<4096, 256, 0, stream>>>(fn, simh);
    scan_kernel<<<4096, 256, 0, stream>>>(simh, prob, parts);
    final_kernel<<<1, 256, 0, stream>>>(parts, out);
}

// Round 7
// 171.285 us; speedup vs baseline: 2.5741x; 1.0970x over previous
//
#include <hip/hip_runtime.h>
#include <hip/hip_bf16.h>

typedef _Float16 half8 __attribute__((ext_vector_type(8)));
typedef float floatx4 __attribute__((ext_vector_type(4)));

#define B_ 4
#define C_ 256
#define N_ 4096

// workspace layout (bytes)
#define OFF_FN    ((size_t)0)                     // 4*4096*256 fp16 = 8 MB
#define OFF_PROB  ((size_t)(8u << 20))            // 16384 fp32 = 64 KB
#define OFF_PART  (OFF_PROB + 65536)              // 4096 fp32 block partials = 16 KB
#define OFF_TOP   ((size_t)(16u << 20))           // 16384 rows x 32 jtiles x 8 u32 = 16 MB

__device__ __forceinline__ void gl_lds16(const void* g, void* l) {
    __builtin_amdgcn_global_load_lds(
        (const __attribute__((address_space(1))) void*)g,
        (__attribute__((address_space(3))) void*)l,
        16, 0, 0);
}

// fp32 -> fp16 (RTN) -> order-preserving u16 flip, packed with 12-bit column index.
// Selection on these u32 is value-exact wrt fp16 sim; j recovered from low bits.
__device__ __forceinline__ uint32_t packf(float v, int j) {
    uint32_t bits = (uint32_t)__builtin_bit_cast(unsigned short, (_Float16)v);
    uint32_t m = ((bits >> 15) * 0x7FFFu) + 0x8000u;   // neg->0xFFFF, pos->0x8000
    return ((bits ^ m) << 16) | (uint32_t)j;
}

// branchless sorted-insert into descending pk[0..7]: 16 v_max/v_min, no branches
__device__ __forceinline__ void ins8(uint32_t u, uint32_t pk[8]) {
    uint32_t c = u;
#pragma unroll
    for (int i = 0; i < 8; ++i) {
        uint32_t hi = max(pk[i], c);
        c = min(pk[i], c);
        pk[i] = hi;
    }
}

// ---------------- Kernel 1: fused prep — reads feats once ----------------
#define TS 68
__global__ __launch_bounds__(256) void prep_kernel(const float* __restrict__ feats,
                                                   const float* __restrict__ logits,
                                                   _Float16* __restrict__ fn,
                                                   float* __restrict__ prob) {
    __shared__ __align__(16) float T[C_ * TS];
    __shared__ float S[256];
    __shared__ float I[64];

    const int t  = threadIdx.x;
    const int b  = blockIdx.x >> 6;
    const int i0 = (blockIdx.x & 63) * 64;
    const float* fb = feats + (size_t)b * C_ * N_;

#pragma unroll
    for (int k = 0; k < 16; ++k) {
        int ch = t + k * 256;
        int row = ch >> 4, col4 = ch & 15;
        float4 v = *(const float4*)(fb + (size_t)row * N_ + i0 + col4 * 4);
        *(float4*)&T[row * TS + col4 * 4] = v;
    }
    __syncthreads();
    {
        int i = t & 63, cq = t >> 6;
        float ss = 0.f;
#pragma unroll 8
        for (int j = 0; j < 64; ++j) { float v = T[(cq * 64 + j) * TS + i]; ss += v * v; }
        S[cq * 64 + i] = ss;
    }
    __syncthreads();
    if (t < 64) {
        float ss = S[t] + S[64 + t] + S[128 + t] + S[192 + t];
        I[t] = 1.f / fmaxf(sqrtf(ss), 1e-12f);
        float lg = logits[b * N_ + i0 + t];
        prob[b * N_ + i0 + t] = 1.f / (1.f + expf(-lg));
    }
    __syncthreads();
    {
        int i = t >> 2, chunk = t & 3;
        float s = I[i];
        _Float16* fr = fn + ((size_t)(b * N_ + i0 + i)) * C_ + chunk * 64;
#pragma unroll
        for (int v8 = 0; v8 < 8; ++v8) {
            half8 h;
#pragma unroll
            for (int e = 0; e < 8; ++e)
                h[e] = (_Float16)(T[(chunk * 64 + v8 * 8 + e) * TS + i] * s);
            *(half8*)(fr + v8 * 8) = h;
        }
    }
}

// ---------------- Kernel 2: MFMA gram tile + fused per-row top-8 partials ----------------
// No sim materialization: tile values are packed (flipped fp16 | col) and selected
// in-block; each (row, jtile) emits its top-8 as 8 u32.
#define CSS 33   // Cs stride (u32)
__global__ __launch_bounds__(256) void gram_sel_kernel(const _Float16* __restrict__ fn,
                                                       uint32_t* __restrict__ top) {
    __shared__ __align__(16) _Float16 As[128 * 64];   // 16 KB
    __shared__ __align__(16) _Float16 Bs[128 * 64];   // 16 KB
    __shared__ __align__(16) uint32_t Cs[128 * CSS];  // 16.9 KB (reused for pair-merge)

    const int t    = threadIdx.x;
    const int lane = t & 63;
    const int w    = t >> 6;
    const int m16  = lane & 15;
    const int q    = lane >> 4;

    const int it = blockIdx.x & 31, jt = (blockIdx.x >> 5) & 31;
    const int b  = blockIdx.x >> 10;
    const int i0 = it * 128, j0 = jt * 128;
    const _Float16* fnb = fn + (size_t)b * N_ * C_;

    const int srowb = t >> 3;
    const int schunk = (t & 7) ^ (srowb & 7);
    const int sw = m16 & 7;

    floatx4 acc[2][8];
#pragma unroll
    for (int ri = 0; ri < 2; ++ri)
#pragma unroll
        for (int jj = 0; jj < 8; ++jj) acc[ri][jj] = floatx4{0.f, 0.f, 0.f, 0.f};

    for (int kc = 0; kc < 4; ++kc) {
#pragma unroll
        for (int r = 0; r < 4; ++r) {
            int row = r * 32 + srowb;
            const _Float16* gA = fnb + (size_t)(i0 + row) * C_ + kc * 64 + schunk * 8;
            const _Float16* gB = fnb + (size_t)(j0 + row) * C_ + kc * 64 + schunk * 8;
            gl_lds16(gA, (char*)As + r * 4096 + t * 16);
            gl_lds16(gB, (char*)Bs + r * 4096 + t * 16);
        }
        __syncthreads();
#pragma unroll
        for (int kk = 0; kk < 2; ++kk) {
            half8 a0 = *(const half8*)&As[(w * 32 + m16) * 64 + ((kk * 4 + q) ^ sw) * 8];
            half8 a1 = *(const half8*)&As[(w * 32 + 16 + m16) * 64 + ((kk * 4 + q) ^ sw) * 8];
#pragma unroll
            for (int jj = 0; jj < 8; ++jj) {
                half8 bf = *(const half8*)&Bs[(jj * 16 + m16) * 64 + ((kk * 4 + q) ^ sw) * 8];
                acc[0][jj] = __builtin_amdgcn_mfma_f32_16x16x32_f16(a0, bf, acc[0][jj], 0, 0, 0);
                acc[1][jj] = __builtin_amdgcn_mfma_f32_16x16x32_f16(a1, bf, acc[1][jj], 0, 0, 0);
            }
        }
        __syncthreads();
    }

    // ---- fused selection: 4 slices of 32 cols through Cs ----
    uint32_t pk[8];
#pragma unroll
    for (int s = 0; s < 8; ++s) pk[s] = 0u;

#pragma unroll
    for (int s = 0; s < 4; ++s) {
        // write slice: pack value+col; storage col swizzled by +8*w (j is in the
        // packed bits, so the reader never needs to unswizzle)
#pragma unroll
        for (int jh = 0; jh < 2; ++jh) {
            const int jj = s * 2 + jh;
            const int jglob = j0 + s * 32 + jh * 16 + m16;
            const int colp = (jh * 16 + m16 + w * 8) & 31;
#pragma unroll
            for (int ri = 0; ri < 2; ++ri)
#pragma unroll
                for (int r = 0; r < 4; ++r) {
                    int row = w * 32 + ri * 16 + q * 4 + r;
                    Cs[row * CSS + colp] = packf(acc[ri][jj][r], jglob);
                }
        }
        __syncthreads();
        // scan slice: 2 threads per row, 16 candidates each (4x b128)
        {
            const uint32_t* cr = &Cs[(t >> 1) * CSS + (t & 1) * 16];
#pragma unroll
            for (int c4 = 0; c4 < 4; ++c4) {
                uint4 u4 = *(const uint4*)(cr + c4 * 4);
                ins8(u4.x, pk); ins8(u4.y, pk); ins8(u4.z, pk); ins8(u4.w, pk);
            }
        }
        __syncthreads();
    }

    // ---- pair merge (2 threads/row) via bitonic identity, emit 8 u32 per row ----
#pragma unroll
    for (int s = 0; s < 8; ++s) Cs[t * 8 + s] = pk[s];
    __syncthreads();
    if ((t & 1) == 0) {
        const uint32_t* pr = &Cs[(t | 1) * 8];
        uint32_t o[8];
#pragma unroll
        for (int i = 0; i < 8; ++i) o[i] = max(pk[i], pr[7 - i]);   // top8 of union
        size_t rowg = (size_t)b * N_ + i0 + (t >> 1);
        uint32_t* dst = top + (rowg * 32 + jt) * 8;
        *(uint4*)dst       = make_uint4(o[0], o[1], o[2], o[3]);
        *(uint4*)(dst + 4) = make_uint4(o[4], o[5], o[6], o[7]);
    }
}

// ---------------- Kernel 3: merge 32 partials/row, gather prob, partial loss ----------------
__global__ __launch_bounds__(256) void merge_kernel(const uint32_t* __restrict__ top,
                                                    const float* __restrict__ prob,
                                                    float* __restrict__ partials) {
    __shared__ float red[4];
    const int t = threadIdx.x;
    const int lane = t & 63;
    const int w = t >> 6;
    const int rg = blockIdx.x * 4 + w;             // 0..16383
    const int b = rg >> 12;

    uint4 v4 = ((const uint4*)(top + (size_t)rg * 256))[lane];
    uint32_t v[4] = {v4.x, v4.y, v4.z, v4.w};
    uint32_t m = max(max(v[0], v[1]), max(v[2], v[3]));

    const float* pb = prob + (b << 12);
    float p_r = prob[rg];
    float contrib = 0.f;
#pragma unroll
    for (int k = 0; k < 8; ++k) {
        uint32_t M = m;
#pragma unroll
        for (int off = 32; off; off >>= 1) M = max(M, (uint32_t)__shfl_xor((int)M, off));
        if (lane == k) contrib = fabsf(p_r - pb[M & 0xFFFu]);
        // branchless invalidate (packed values unique across lanes)
#pragma unroll
        for (int s = 0; s < 4; ++s) v[s] = (v[s] == M) ? 0u : v[s];
        m = max(max(v[0], v[1]), max(v[2], v[3]));
    }
#pragma unroll
    for (int off = 32; off; off >>= 1) contrib += __shfl_xor(contrib, off);
    if (lane == 0) red[w] = contrib;
    __syncthreads();
    if (t == 0) partials[blockIdx.x] = red[0] + red[1] + red[2] + red[3];
}

// ---------------- Kernel 4: final reduce (4096 partials) ----------------
__global__ __launch_bounds__(256) void final_kernel(const float* __restrict__ partials,
                                                    float* __restrict__ out) {
    __shared__ float red[256];
    int t = threadIdx.x;
    float s = 0.f;
#pragma unroll
    for (int k = 0; k < 16; ++k) s += partials[k * 256 + t];
    red[t] = s;
    __syncthreads();
    for (int off = 128; off > 0; off >>= 1) {
        if (t < off) red[t] += red[t + off];
        __syncthreads();
    }
    if (t == 0) out[0] = red[0] * (1.f / (B_ * N_ * 8.0f));
}

extern "C" void kernel_launch(void* const* d_in, const int* in_sizes, int n_in,
                              void* d_out, int out_size, void* d_ws, size_t ws_size,
                              hipStream_t stream) {
    const float* feats  = (const float*)d_in[0];
    const float* logits = (const float*)d_in[1];
    float* out = (float*)d_out;
    char* ws = (char*)d_ws;
    _Float16* fn   = (_Float16*)(ws + OFF_FN);
    float* prob    = (float*)(ws + OFF_PROB);
    float* parts   = (float*)(ws + OFF_PART);
    uint32_t* top  = (uint32_t*)(ws + OFF_TOP);

    prep_kernel<<<256, 256, 0, stream>>>(feats, logits, fn, prob);
    gram_sel_kernel<<<4096, 256, 0, stream>>>(fn, top);
    merge_kernel<<<4096, 256, 0, stream>>>(top, prob, parts);
    final_kernel<<<1, 256, 0, stream>>>(parts, out);
}

// Round 8
// 137.084 us; speedup vs baseline: 3.2163x; 1.2495x over previous
//
#include <hip/hip_runtime.h>
#include <hip/hip_bf16.h>

typedef _Float16 half8 __attribute__((ext_vector_type(8)));
typedef unsigned short ushort8 __attribute__((ext_vector_type(8)));
typedef float floatx4 __attribute__((ext_vector_type(4)));

#define B_ 4
#define C_ 256
#define N_ 4096
#define NT 32            // 128-wide tiles per dim
#define TRI 528          // NT*(NT+1)/2 triangular tiles per batch

// workspace layout (bytes)
#define OFF_FN    ((size_t)0)                     // 4*4096*256 fp16 = 8 MB
#define OFF_PROB  ((size_t)(8u << 20))            // 16384 fp32 = 64 KB
#define OFF_PART  (OFF_PROB + 65536)              // 4096 fp32 block partials = 16 KB
#define OFF_TOP   ((size_t)(16u << 20))           // 16384 rows x 32 jtiles x 8 u32 = 16 MB

__device__ __forceinline__ void gl_lds16(const void* g, void* l) {
    __builtin_amdgcn_global_load_lds(
        (const __attribute__((address_space(1))) void*)g,
        (__attribute__((address_space(3))) void*)l,
        16, 0, 0);
}

// fp32 -> fp16 (RTN) -> order-preserving u16 flip (selection value-exact wrt fp16 sim)
__device__ __forceinline__ unsigned short flip16(float v) {
    uint32_t bits = (uint32_t)__builtin_bit_cast(unsigned short, (_Float16)v);
    return (unsigned short)(bits ^ (((bits >> 15) * 0x7FFFu) + 0x8000u));
}

__device__ __forceinline__ void cas(uint32_t& a, uint32_t& b) {
    uint32_t hi = max(a, b); b = min(a, b); a = hi;
}

// Batcher odd-even mergesort, 8 elems, descending (19 CAS)
__device__ __forceinline__ void sort8(uint32_t v[8]) {
    cas(v[0],v[1]); cas(v[2],v[3]); cas(v[4],v[5]); cas(v[6],v[7]);
    cas(v[0],v[2]); cas(v[1],v[3]); cas(v[4],v[6]); cas(v[5],v[7]);
    cas(v[1],v[2]); cas(v[5],v[6]);
    cas(v[0],v[4]); cas(v[1],v[5]); cas(v[2],v[6]); cas(v[3],v[7]);
    cas(v[2],v[4]); cas(v[3],v[5]);
    cas(v[1],v[2]); cas(v[3],v[4]); cas(v[5],v[6]);
}

// r, n desc-sorted -> r = top-8 of union, desc-sorted (8 max + 12 CAS)
__device__ __forceinline__ void merge8(uint32_t r[8], const uint32_t n[8]) {
    uint32_t m[8];
#pragma unroll
    for (int i = 0; i < 8; ++i) m[i] = max(r[i], n[7 - i]);   // bitonic
    cas(m[0],m[4]); cas(m[1],m[5]); cas(m[2],m[6]); cas(m[3],m[7]);
    cas(m[0],m[2]); cas(m[1],m[3]); cas(m[4],m[6]); cas(m[5],m[7]);
    cas(m[0],m[1]); cas(m[2],m[3]); cas(m[4],m[5]); cas(m[6],m[7]);
#pragma unroll
    for (int i = 0; i < 8; ++i) r[i] = m[i];
}

// ---------------- Kernel 1: fused prep — reads feats once ----------------
#define TS 68
__global__ __launch_bounds__(256) void prep_kernel(const float* __restrict__ feats,
                                                   const float* __restrict__ logits,
                                                   _Float16* __restrict__ fn,
                                                   float* __restrict__ prob) {
    __shared__ __align__(16) float T[C_ * TS];
    __shared__ float S[256];
    __shared__ float I[64];

    const int t  = threadIdx.x;
    const int b  = blockIdx.x >> 6;
    const int i0 = (blockIdx.x & 63) * 64;
    const float* fb = feats + (size_t)b * C_ * N_;

#pragma unroll
    for (int k = 0; k < 16; ++k) {
        int ch = t + k * 256;
        int row = ch >> 4, col4 = ch & 15;
        float4 v = *(const float4*)(fb + (size_t)row * N_ + i0 + col4 * 4);
        *(float4*)&T[row * TS + col4 * 4] = v;
    }
    __syncthreads();
    {
        int i = t & 63, cq = t >> 6;
        float ss = 0.f;
#pragma unroll 8
        for (int j = 0; j < 64; ++j) { float v = T[(cq * 64 + j) * TS + i]; ss += v * v; }
        S[cq * 64 + i] = ss;
    }
    __syncthreads();
    if (t < 64) {
        float ss = S[t] + S[64 + t] + S[128 + t] + S[192 + t];
        I[t] = 1.f / fmaxf(sqrtf(ss), 1e-12f);
        float lg = logits[b * N_ + i0 + t];
        prob[b * N_ + i0 + t] = 1.f / (1.f + expf(-lg));
    }
    __syncthreads();
    {
        int i = t >> 2, chunk = t & 3;
        float s = I[i];
        _Float16* fr = fn + ((size_t)(b * N_ + i0 + i)) * C_ + chunk * 64;
#pragma unroll
        for (int v8 = 0; v8 < 8; ++v8) {
            half8 h;
#pragma unroll
            for (int e = 0; e < 8; ++e)
                h[e] = (_Float16)(T[(chunk * 64 + v8 * 8 + e) * TS + i] * s);
            *(half8*)(fr + v8 * 8) = h;
        }
    }
}

// ---------------- Kernel 2: triangular MFMA gram tile + dual-scan top-8 ----------------
// Only it<=jt tiles computed (Gram symmetry). Full 128x128 flipped-u16 tile kept in
// LDS (aliasing As/Bs, dead after K-loop); row-scan -> i-side partials, col-scan ->
// j-side partials (off-diag only). Sorting-network selection (~9 ops/cand).
#define CSH 132   // u16 tile stride: 66 u32-banks/row == 2 mod 32 -> 2-way only (free)
__global__ __launch_bounds__(256) void gram_sel_kernel(const _Float16* __restrict__ fn,
                                                       uint32_t* __restrict__ top) {
    __shared__ __align__(16) char smem[128 * CSH * 2];   // 33792 B
    _Float16* As = (_Float16*)smem;                      // 16 KB (K-loop)
    _Float16* Bs = (_Float16*)(smem + 16384);            // 16 KB (K-loop)
    unsigned short* Ch = (unsigned short*)smem;          // 128 x CSH u16 (selection)
    uint32_t* Ms = (uint32_t*)smem;                      // pair-merge staging

    const int t    = threadIdx.x;
    const int lane = t & 63;
    const int w    = t >> 6;
    const int m16  = lane & 15;
    const int q    = lane >> 4;

    // triangular block index -> (b, it, jt) with it <= jt
    const int b = blockIdx.x / TRI;
    const int u = blockIdx.x - b * TRI;
    int it = (int)(32.5f - sqrtf(32.5f * 32.5f - 2.0f * (float)u));
    while (u >= (it + 1) * (65 - (it + 1)) / 2) ++it;    // offset(it) = it*(65-it)/2
    while (u < it * (65 - it) / 2) --it;
    const int jt = it + (u - it * (65 - it) / 2);
    const bool diag = (it == jt);

    const int i0 = it * 128, j0 = jt * 128;
    const _Float16* fnb = fn + (size_t)b * N_ * C_;

    const int srowb = t >> 3;
    const int schunk = (t & 7) ^ (srowb & 7);
    const int sw = m16 & 7;

    floatx4 acc[2][8];
#pragma unroll
    for (int ri = 0; ri < 2; ++ri)
#pragma unroll
        for (int jj = 0; jj < 8; ++jj) acc[ri][jj] = floatx4{0.f, 0.f, 0.f, 0.f};

    for (int kc = 0; kc < 4; ++kc) {
#pragma unroll
        for (int r = 0; r < 4; ++r) {
            int row = r * 32 + srowb;
            const _Float16* gA = fnb + (size_t)(i0 + row) * C_ + kc * 64 + schunk * 8;
            const _Float16* gB = fnb + (size_t)(j0 + row) * C_ + kc * 64 + schunk * 8;
            gl_lds16(gA, (char*)As + r * 4096 + t * 16);
            gl_lds16(gB, (char*)Bs + r * 4096 + t * 16);
        }
        __syncthreads();
#pragma unroll
        for (int kk = 0; kk < 2; ++kk) {
            half8 a0 = *(const half8*)&As[(w * 32 + m16) * 64 + ((kk * 4 + q) ^ sw) * 8];
            half8 a1 = *(const half8*)&As[(w * 32 + 16 + m16) * 64 + ((kk * 4 + q) ^ sw) * 8];
#pragma unroll
            for (int jj = 0; jj < 8; ++jj) {
                half8 bf = *(const half8*)&Bs[(jj * 16 + m16) * 64 + ((kk * 4 + q) ^ sw) * 8];
                acc[0][jj] = __builtin_amdgcn_mfma_f32_16x16x32_f16(a0, bf, acc[0][jj], 0, 0, 0);
                acc[1][jj] = __builtin_amdgcn_mfma_f32_16x16x32_f16(a1, bf, acc[1][jj], 0, 0, 0);
            }
        }
        __syncthreads();
    }

    // ---- dump full tile as flipped u16 (C/D layout: col=lane&15, row=q*4+reg) ----
#pragma unroll
    for (int jj = 0; jj < 8; ++jj)
#pragma unroll
        for (int ri = 0; ri < 2; ++ri)
#pragma unroll
            for (int r = 0; r < 4; ++r) {
                int row = w * 32 + ri * 16 + q * 4 + r;
                Ch[row * CSH + jj * 16 + m16] = flip16(acc[ri][jj][r]);
            }
    __syncthreads();

    // ---- row-scan: 2 threads/row, 64 cols each, b128 reads ----
    uint32_t rowpk[8], colpk[8];
    {
        const int rrow = t >> 1, rc0 = (t & 1) * 64;
        const unsigned short* cr = &Ch[rrow * CSH + rc0];
        const int jbase = j0 + rc0;
#pragma unroll
        for (int g = 0; g < 8; ++g) {
            ushort8 v = *(const ushort8*)(cr + g * 8);
            uint32_t cand[8];
#pragma unroll
            for (int e = 0; e < 8; ++e)
                cand[e] = ((uint32_t)v[e] << 16) | (uint32_t)(jbase + g * 8 + e);
            sort8(cand);
            if (g == 0) {
#pragma unroll
                for (int s = 0; s < 8; ++s) rowpk[s] = cand[s];
            } else merge8(rowpk, cand);
        }
    }
    // ---- col-scan (off-diag only): 2 threads/col, 64 rows each ----
    if (!diag) {
        const int ccol = t >> 1, cr0 = (t & 1) * 64;
        const unsigned short* cc = &Ch[cr0 * CSH + ccol];
        const int ibase = i0 + cr0;
#pragma unroll
        for (int g = 0; g < 8; ++g) {
            uint32_t cand[8];
#pragma unroll
            for (int e = 0; e < 8; ++e)
                cand[e] = ((uint32_t)cc[(g * 8 + e) * CSH] << 16) | (uint32_t)(ibase + g * 8 + e);
            sort8(cand);
            if (g == 0) {
#pragma unroll
                for (int s = 0; s < 8; ++s) colpk[s] = cand[s];
            } else merge8(colpk, cand);
        }
    }
    __syncthreads();   // scans done reading Ch; reuse as merge staging

    // ---- pair-merge across the 2 threads of each row/col, emit 8 u32 ----
    if (t & 1) {
#pragma unroll
        for (int s = 0; s < 8; ++s) Ms[(t >> 1) * 8 + s] = rowpk[s];
        if (!diag) {
#pragma unroll
            for (int s = 0; s < 8; ++s) Ms[1024 + (t >> 1) * 8 + s] = colpk[s];
        }
    }
    __syncthreads();
    if (!(t & 1)) {
        uint32_t o[8];
#pragma unroll
        for (int s = 0; s < 8; ++s) o[s] = Ms[(t >> 1) * 8 + s];
        merge8(rowpk, o);
        uint32_t* dst = top + (((size_t)b * N_ + i0 + (t >> 1)) * 32 + jt) * 8;
        *(uint4*)dst       = make_uint4(rowpk[0], rowpk[1], rowpk[2], rowpk[3]);
        *(uint4*)(dst + 4) = make_uint4(rowpk[4], rowpk[5], rowpk[6], rowpk[7]);
        if (!diag) {
#pragma unroll
            for (int s = 0; s < 8; ++s) o[s] = Ms[1024 + (t >> 1) * 8 + s];
            merge8(colpk, o);
            uint32_t* dst2 = top + (((size_t)b * N_ + j0 + (t >> 1)) * 32 + it) * 8;
            *(uint4*)dst2       = make_uint4(colpk[0], colpk[1], colpk[2], colpk[3]);
            *(uint4*)(dst2 + 4) = make_uint4(colpk[4], colpk[5], colpk[6], colpk[7]);
        }
    }
}

// ---------------- Kernel 3: merge 32 partials/row, gather prob, partial loss ----------------
__global__ __launch_bounds__(256) void merge_kernel(const uint32_t* __restrict__ top,
                                                    const float* __restrict__ prob,
                                                    float* __restrict__ partials) {
    __shared__ float red[4];
    const int t = threadIdx.x;
    const int lane = t & 63;
    const int w = t >> 6;
    const int rg = blockIdx.x * 4 + w;             // 0..16383
    const int b = rg >> 12;

    uint4 v4 = ((const uint4*)(top + (size_t)rg * 256))[lane];
    uint32_t v[4] = {v4.x, v4.y, v4.z, v4.w};
    uint32_t m = max(max(v[0], v[1]), max(v[2], v[3]));

    const float* pb = prob + (b << 12);
    float p_r = prob[rg];
    float contrib = 0.f;
#pragma unroll
    for (int k = 0; k < 8; ++k) {
        uint32_t M = m;
#pragma unroll
        for (int off = 32; off; off >>= 1) M = max(M, (uint32_t)__shfl_xor((int)M, off));
        if (lane == k) contrib = fabsf(p_r - pb[M & 0xFFFu]);
#pragma unroll
        for (int s = 0; s < 4; ++s) v[s] = (v[s] == M) ? 0u : v[s];
        m = max(max(v[0], v[1]), max(v[2], v[3]));
    }
#pragma unroll
    for (int off = 32; off; off >>= 1) contrib += __shfl_xor(contrib, off);
    if (lane == 0) red[w] = contrib;
    __syncthreads();
    if (t == 0) partials[blockIdx.x] = red[0] + red[1] + red[2] + red[3];
}

// ---------------- Kernel 4: final reduce (4096 partials) ----------------
__global__ __launch_bounds__(256) void final_kernel(const float* __restrict__ partials,
                                                    float* __restrict__ out) {
    __shared__ float red[256];
    int t = threadIdx.x;
    float s = 0.f;
#pragma unroll
    for (int k = 0; k < 16; ++k) s += partials[k * 256 + t];
    red[t] = s;
    __syncthreads();
    for (int off = 128; off > 0; off >>= 1) {
        if (t < off) red[t] += red[t + off];
        __syncthreads();
    }
    if (t == 0) out[0] = red[0] * (1.f / (B_ * N_ * 8.0f));
}

extern "C" void kernel_launch(void* const* d_in, const int* in_sizes, int n_in,
                              void* d_out, int out_size, void* d_ws, size_t ws_size,
                              hipStream_t stream) {
    const float* feats  = (const float*)d_in[0];
    const float* logits = (const float*)d_in[1];
    float* out = (float*)d_out;
    char* ws = (char*)d_ws;
    _Float16* fn   = (_Float16*)(ws + OFF_FN);
    float* prob    = (float*)(ws + OFF_PROB);
    float* parts   = (float*)(ws + OFF_PART);
    uint32_t* top  = (uint32_t*)(ws + OFF_TOP);

    prep_kernel<<<256, 256, 0, stream>>>(feats, logits, fn, prob);
    gram_sel_kernel<<<B_ * TRI, 256, 0, stream>>>(fn, top);
    merge_kernel<<<4096, 256, 0, stream>>>(top, prob, parts);
    final_kernel<<<1, 256, 0, stream>>>(parts, out);
}